// Round 3
// baseline (585.551 us; speedup 1.0000x reference)
//
#include <hip/hip_runtime.h>
#include <hip/hip_bf16.h>

#define NROWS 32768
#define DIM   512
#define HEADS 8
#define LN_EPS 1e-5f

typedef __attribute__((ext_vector_type(8))) short short8;   // 8 bf16 (4 VGPRs)
typedef __attribute__((ext_vector_type(4))) float floatx4;  // MFMA acc

typedef __attribute__((address_space(3))) void lds_void;
typedef __attribute__((address_space(1))) void gbl_void;

// async global->LDS, 16 B per lane; LDS dest = wave-uniform base + lane*16
__device__ __forceinline__ void async16(const void* g, void* l) {
    __builtin_amdgcn_global_load_lds(
        (gbl_void*)(unsigned long long)(uintptr_t)g,
        (lds_void*)(unsigned int)(uintptr_t)l,
        16, 0, 0);
}

// ---------------------------------------------------------------------------
// h (fp32) -> hb (bf16), vectorized
// ---------------------------------------------------------------------------
__global__ __launch_bounds__(256) void hconv_kernel(
    const float* __restrict__ h, __hip_bfloat16* __restrict__ hb)
{
    const size_t i = ((size_t)blockIdx.x * 256 + threadIdx.x) * 4;
    const float4 f = *(const float4*)(h + i);
    union { ushort4 u; __hip_bfloat16 b[4]; } pk;
    pk.b[0] = __float2bfloat16(f.x);
    pk.b[1] = __float2bfloat16(f.y);
    pk.b[2] = __float2bfloat16(f.z);
    pk.b[3] = __float2bfloat16(f.w);
    *(ushort4*)(hb + i) = pk.u;
}

// ---------------------------------------------------------------------------
// W [K=512][N=512] fp32 -> Wt [N][K] bf16 (transpose + convert), 32x32 tiles
// ---------------------------------------------------------------------------
__global__ __launch_bounds__(256) void wtrans_kernel(
    const float* __restrict__ W, __hip_bfloat16* __restrict__ Wt)
{
    __shared__ float tile[32][33];
    const int bn = blockIdx.x * 32;
    const int bk = blockIdx.y * 32;
    const int tx = threadIdx.x & 31;
    const int ty = threadIdx.x >> 5;
    #pragma unroll
    for (int i = ty; i < 32; i += 8)
        tile[i][tx] = W[(size_t)(bk + i) * DIM + bn + tx];
    __syncthreads();
    #pragma unroll
    for (int i = ty; i < 32; i += 8)
        Wt[(size_t)(bn + i) * DIM + bk + tx] = __float2bfloat16(tile[tx][i]);
}

// ---------------------------------------------------------------------------
// Barrier-free short-K MFMA GEMM (multi-matrix fused).
//   C_m[M,512] = A[M,512](bf16) @ Bt_m[n][k](bf16)^T,  m = blockIdx.x>>1
// Block: 64 rows x 256 cols. 4 waves, each 64x64 (4x4 16x16x32 frags).
// A panel (64x512 bf16 = 64 KB) staged in LDS ONCE (global_load_lds w=16,
// XOR swizzle slot = kc ^ (row&7) -> frag ds_read_b128 is 2-lane/bank =
// ideal 8-phase). K-loop has NO barriers: A from LDS, B direct global->reg
// (L2-resident; each frag load = 16 rows x 64 B contiguous lines).
// ---------------------------------------------------------------------------
__global__ __launch_bounds__(256, 2) void gemm_kernel(
    const __hip_bfloat16* __restrict__ A,
    const __hip_bfloat16* __restrict__ Bt_base,
    float* __restrict__ C_base, int relu_mask)
{
    __shared__ __align__(16) char smem[65536];   // 64 rows x 64 chunks x 16 B

    const int t    = threadIdx.x;
    const int lane = t & 63;
    const int w    = t >> 6;
    const int l16  = lane & 15, quad = lane >> 4;
    const int mat  = blockIdx.x >> 1;
    const int nb   = blockIdx.x & 1;
    const int bm   = blockIdx.y * 64;
    const int relu = (relu_mask >> mat) & 1;
    const int nbase = nb * 256 + w * 64;

    const __hip_bfloat16* Bt = Bt_base + (size_t)mat * DIM * DIM;
    float* C = C_base + (size_t)mat * (size_t)NROWS * DIM;

    // ---- stage A rows [bm, bm+64): row r slot s holds logical chunk s^(r&7)
    #pragma unroll
    for (int i = 0; i < 16; ++i) {
        const int r = w * 16 + i;
        async16(A + (size_t)(bm + r) * DIM + (lane ^ (r & 7)) * 8,
                smem + r * 1024 + lane * 16);
    }

    // ---- B frag global pointers (frag j: col nbase+j*16+l16, k-chunk quad)
    const __hip_bfloat16* bptr[4];
    #pragma unroll
    for (int j = 0; j < 4; ++j)
        bptr[j] = Bt + (size_t)(nbase + j * 16 + l16) * DIM + quad * 8;

    // ---- A frag LDS even-kit base; odd kit = base ^ 64 (bit 6 = slot bit 2)
    int aoffE[4];
    #pragma unroll
    for (int i = 0; i < 4; ++i) {
        const int m = i * 16 + l16;
        aoffE[i] = m * 1024 + ((quad ^ (m & 7)) & 7) * 16;
    }

    floatx4 acc[16];
    #pragma unroll
    for (int i = 0; i < 16; ++i) acc[i] = (floatx4){0.f, 0.f, 0.f, 0.f};

    __syncthreads();   // drains global_load_lds (vmcnt) + joins waves

    // ---- barrier-free K loop: 16 iters of K=32
    #pragma unroll 4
    for (int kit = 0; kit < 16; ++kit) {
        short8 bfv[4], af[4];
        #pragma unroll
        for (int j = 0; j < 4; ++j)
            bfv[j] = *(const short8*)(bptr[j] + kit * 32);
        #pragma unroll
        for (int i = 0; i < 4; ++i)
            af[i] = *(const short8*)(smem + ((aoffE[i] ^ ((kit & 1) << 6))
                                             + (kit >> 1) * 128));
        #pragma unroll
        for (int i = 0; i < 4; ++i)
            #pragma unroll
            for (int j = 0; j < 4; ++j)
                acc[i * 4 + j] = __builtin_amdgcn_mfma_f32_16x16x32_bf16(
                    af[i], bfv[j], acc[i * 4 + j], 0, 0, 0);
    }

    // ---- epilogue: D row = quad*4 + reg, col = lane&15  [m89]
    #pragma unroll
    for (int i = 0; i < 4; ++i) {
        const int gr = bm + i * 16 + quad * 4;
        #pragma unroll
        for (int j = 0; j < 4; ++j) {
            const int gc = nbase + j * 16 + l16;
            floatx4 v = acc[i * 4 + j];
            #pragma unroll
            for (int rg = 0; rg < 4; ++rg) {
                float vv = v[rg];
                if (relu) vv = fmaxf(vv, 0.f);
                C[(size_t)(gr + rg) * DIM + gc] = vv;
            }
        }
    }
}

// ---------------------------------------------------------------------------
// Linear attention, 2 rows per block (128 thr each), float4 LDS paths.
// Writes attn directly as bf16 (input to the Wf GEMM).
// ---------------------------------------------------------------------------
__global__ __launch_bounds__(256) void attn_kernel(
    const float* __restrict__ q, const float* __restrict__ k,
    const float* __restrict__ v, __hip_bfloat16* __restrict__ attn)
{
    __shared__ float sq[2][DIM], sk[2][DIM], sv[2][DIM];
    __shared__ float skv[2][64][68];
    __shared__ float sksum[2][64];

    const int t = threadIdx.x;
    const int r = t >> 7;
    const int u = t & 127;
    const size_t base = ((size_t)blockIdx.x * 2 + r) * DIM;

    ((float4*)sq[r])[u] = ((const float4*)(q + base))[u];
    ((float4*)sk[r])[u] = ((const float4*)(k + base))[u];
    ((float4*)sv[r])[u] = ((const float4*)(v + base))[u];
    __syncthreads();

    const int e0 = (u & 15) * 4;
    const int d0 = (u >> 4) * 8;

    if (u < 64) {
        float s = 0.f;
        #pragma unroll
        for (int h = 0; h < HEADS; ++h) s += sk[r][h * 64 + u];
        sksum[r][u] = s;
    }

    float4 acc[8];
    #pragma unroll
    for (int i = 0; i < 8; ++i) acc[i] = make_float4(0.f, 0.f, 0.f, 0.f);
    #pragma unroll
    for (int h = 0; h < HEADS; ++h) {
        const float4 v4 = *(const float4*)&sv[r][h * 64 + e0];
        #pragma unroll
        for (int i = 0; i < 8; ++i) {
            const float kd = sk[r][h * 64 + d0 + i];
            acc[i].x += kd * v4.x; acc[i].y += kd * v4.y;
            acc[i].z += kd * v4.z; acc[i].w += kd * v4.w;
        }
    }
    #pragma unroll
    for (int i = 0; i < 8; ++i)
        *(float4*)&skv[r][d0 + i][e0] = acc[i];
    __syncthreads();

    const int n = u >> 4;
    float sx = 0.f, sy = 0.f, sz = 0.f, sw = 0.f, den = 0.f;
    #pragma unroll 8
    for (int d = 0; d < 64; ++d) {
        const float qd = sq[r][n * 64 + d];
        const float4 kv4 = *(const float4*)&skv[r][d][e0];
        sx += qd * kv4.x; sy += qd * kv4.y;
        sz += qd * kv4.z; sw += qd * kv4.w;
        den += qd * sksum[r][d];
    }
    union { ushort4 us; __hip_bfloat16 b[4]; } pk;
    pk.b[0] = __float2bfloat16(sx / den);
    pk.b[1] = __float2bfloat16(sy / den);
    pk.b[2] = __float2bfloat16(sz / den);
    pk.b[3] = __float2bfloat16(sw / den);
    *(ushort4*)(attn + base + n * 64 + e0) = pk.us;
}

// ---------------------------------------------------------------------------
// LayerNorm(h + fh)*gamma + beta — one wave per row, 4 rows/block.
// fh aliases out (same-address read-then-write per thread) — no __restrict__.
// ---------------------------------------------------------------------------
__global__ __launch_bounds__(256) void ln_kernel(
    const float* __restrict__ h, const float* fh,
    const float* __restrict__ gamma, const float* __restrict__ beta,
    float* out)
{
    const int lane = threadIdx.x & 63;
    const int wave = threadIdx.x >> 6;
    const size_t base = ((size_t)blockIdx.x * 4 + wave) * DIM;

    float x[8];
    float s = 0.f;
    #pragma unroll
    for (int i = 0; i < 8; ++i) {
        const int j = lane + i * 64;
        x[i] = h[base + j] + fh[base + j];
        s += x[i];
    }
    #pragma unroll
    for (int off = 32; off > 0; off >>= 1) s += __shfl_down(s, off);
    const float mu = __shfl(s, 0) * (1.f / DIM);

    float vs = 0.f;
    #pragma unroll
    for (int i = 0; i < 8; ++i) { const float d = x[i] - mu; vs += d * d; }
    #pragma unroll
    for (int off = 32; off > 0; off >>= 1) vs += __shfl_down(vs, off);
    const float rstd = rsqrtf(__shfl(vs, 0) * (1.f / DIM) + LN_EPS);

    #pragma unroll
    for (int i = 0; i < 8; ++i) {
        const int j = lane + i * 64;
        out[base + j] = (x[i] - mu) * rstd * gamma[j] + beta[j];
    }
}

// ---------------------------------------------------------------------------
extern "C" void kernel_launch(void* const* d_in, const int* in_sizes, int n_in,
                              void* d_out, int out_size, void* d_ws, size_t ws_size,
                              hipStream_t stream)
{
    const float* h     = (const float*)d_in[0];
    const float* Wq    = (const float*)d_in[1];
    const float* Wk    = (const float*)d_in[2];
    const float* Wv    = (const float*)d_in[3];
    const float* Wf    = (const float*)d_in[4];
    const float* gamma = (const float*)d_in[5];
    const float* beta  = (const float*)d_in[6];

    const size_t ND = (size_t)NROWS * DIM;
    float* out = (float*)d_out;
    float* qo  = out + ND;            // q,k,v outputs contiguous -> C_base
    float* fh  = out;                 // stage fh in out[0..ND) (dead until LN)

    __hip_bfloat16* hb  = (__hip_bfloat16*)d_ws;     // ND bf16 (32 MB)
    __hip_bfloat16* wtq = hb + ND;                   // Wq^T,Wk^T,Wv^T,Wf^T bf16
    __hip_bfloat16* wtk = wtq + DIM * DIM;
    __hip_bfloat16* wtv = wtk + DIM * DIM;
    __hip_bfloat16* wtf = wtv + DIM * DIM;
    __hip_bfloat16* attnb = hb;       // reuse hb region (dead after QKV GEMM)

    const dim3 wgrid(16, 16);

    hconv_kernel<<<NROWS * DIM / 1024, 256, 0, stream>>>(h, hb);
    wtrans_kernel<<<wgrid, 256, 0, stream>>>(Wq, wtq);
    wtrans_kernel<<<wgrid, 256, 0, stream>>>(Wk, wtk);
    wtrans_kernel<<<wgrid, 256, 0, stream>>>(Wv, wtv);
    wtrans_kernel<<<wgrid, 256, 0, stream>>>(Wf, wtf);

    // fused Q,K,V GEMM: grid.x = matrix(3) x n-half(2); relu on q,k only
    gemm_kernel<<<dim3(6, NROWS / 64), 256, 0, stream>>>(hb, wtq, qo, 0x3);

    attn_kernel<<<NROWS / 2, 256, 0, stream>>>(qo, qo + ND, qo + 2 * ND, attnb);

    // Wf GEMM: single matrix, 2 n-halves
    gemm_kernel<<<dim3(2, NROWS / 64), 256, 0, stream>>>(attnb, wtf, fh, 0x0);

    ln_kernel<<<NROWS / 4, 256, 0, stream>>>(h, fh, gamma, beta, out);
}